// Round 1
// baseline (116.670 us; speedup 1.0000x reference)
//
#include <hip/hip_runtime.h>

// ConvTranspose3d-via-FFT reference == circular 3^3 conv on 2x upsampled grid.
// Parity decomposition: out[b,i,2q+p] needs only taps t in {0,1} on the 16^3
// input grid with combined weights:
//   p=0: t0 <- {k0},    t1 <- {k1,k2}
//   p=1: t0 <- {k0,k1}, t1 <- {k2}
// per axis (circular wrap mod 16 matches ((..)mod 32)>>1 exactly).

#define B_  4
#define CI  64
#define CO  32
#define Q   16          // input spatial size per axis
#define XB_STRIDE (CI*Q*Q*Q)   // 262144
#define OUT_I_STRIDE (32*32*32) // 32768
#define OUT_B_STRIDE (CO*OUT_I_STRIDE)

__global__ __launch_bounds__(256)
void convt3d_parity_kernel(const float* __restrict__ x,
                           const float* __restrict__ weight,
                           float* __restrict__ out) {
    // we[i][j][t], t = td*4+th*2+tw  (64 KB)
    __shared__ float we[CO][CI][8];

    const int blk  = blockIdx.x;
    const int b    = blk >> 7;          // 4
    const int p    = (blk >> 4) & 7;    // 8 parities
    const int tile = blk & 15;          // 16 tiles of 256 q-positions
    const int pd = p >> 2, ph = (p >> 1) & 1, pw = p & 1;

    // ---- build effective weights for this parity ----
    for (int pair = threadIdx.x; pair < CO * CI; pair += 256) {
        const float* wp = weight + pair * 27;
        float wv[27];
        #pragma unroll
        for (int k = 0; k < 27; ++k) wv[k] = wp[k];

        // contract kd -> td
        float t1[2][9];
        #pragma unroll
        for (int m = 0; m < 9; ++m) {
            t1[0][m] = pd ? (wv[m] + wv[9 + m]) : wv[m];
            t1[1][m] = pd ? wv[18 + m] : (wv[9 + m] + wv[18 + m]);
        }
        // contract kh -> th
        float t2[2][2][3];
        #pragma unroll
        for (int td = 0; td < 2; ++td) {
            #pragma unroll
            for (int m = 0; m < 3; ++m) {
                t2[td][0][m] = ph ? (t1[td][m] + t1[td][3 + m]) : t1[td][m];
                t2[td][1][m] = ph ? t1[td][6 + m] : (t1[td][3 + m] + t1[td][6 + m]);
            }
        }
        // contract kw -> tw
        const int i = pair >> 6, j = pair & 63;
        #pragma unroll
        for (int td = 0; td < 2; ++td) {
            #pragma unroll
            for (int th = 0; th < 2; ++th) {
                float a0 = pw ? (t2[td][th][0] + t2[td][th][1]) : t2[td][th][0];
                float a1 = pw ? t2[td][th][2] : (t2[td][th][1] + t2[td][th][2]);
                we[i][j][td * 4 + th * 2 + 0] = a0;
                we[i][j][td * 4 + th * 2 + 1] = a1;
            }
        }
    }
    __syncthreads();

    // ---- per-thread: one q-position, all 32 output channels ----
    const int q  = tile * 256 + threadIdx.x;
    const int qd = q >> 8, qh = (q >> 4) & 15, qw = q & 15;

    int xoff[8];
    #pragma unroll
    for (int t = 0; t < 8; ++t) {
        const int td = t >> 2, th = (t >> 1) & 1, tw = t & 1;
        xoff[t] = ((qd - td) & 15) * 256 + ((qh - th) & 15) * 16 + ((qw - tw) & 15);
    }

    const float* xb = x + b * XB_STRIDE;
    float acc[CO];
    #pragma unroll
    for (int i = 0; i < CO; ++i) acc[i] = 0.f;

    for (int j = 0; j < CI; ++j) {
        float xv[8];
        #pragma unroll
        for (int t = 0; t < 8; ++t) xv[t] = xb[j * (Q*Q*Q) + xoff[t]];
        #pragma unroll
        for (int i = 0; i < CO; ++i) {
            const float4* w4 = reinterpret_cast<const float4*>(&we[i][j][0]);
            const float4 wa = w4[0];
            const float4 wb = w4[1];
            acc[i] += wa.x * xv[0] + wa.y * xv[1] + wa.z * xv[2] + wa.w * xv[3]
                    + wb.x * xv[4] + wb.y * xv[5] + wb.z * xv[6] + wb.w * xv[7];
        }
    }

    const int d = 2 * qd + pd, h = 2 * qh + ph, w_ = 2 * qw + pw;
    float* ob = out + b * OUT_B_STRIDE + d * 1024 + h * 32 + w_;
    #pragma unroll
    for (int i = 0; i < CO; ++i) ob[i * OUT_I_STRIDE] = acc[i];
}

extern "C" void kernel_launch(void* const* d_in, const int* in_sizes, int n_in,
                              void* d_out, int out_size, void* d_ws, size_t ws_size,
                              hipStream_t stream) {
    const float* x      = (const float*)d_in[0];
    const float* weight = (const float*)d_in[1];
    float* out          = (float*)d_out;

    convt3d_parity_kernel<<<512, 256, 0, stream>>>(x, weight, out);
}

// Round 2
// 112.202 us; speedup vs baseline: 1.0398x; 1.0398x over previous
//
#include <hip/hip_runtime.h>

// ConvTranspose3d-via-FFT reference == circular 3^3 conv on 2x upsampled grid.
// Parity decomposition: out[b,i,2q+p] needs only taps t in {0,1} on the 16^3
// input grid with combined weights:
//   p=0: t0 <- {k0},    t1 <- {k1,k2}
//   p=1: t0 <- {k0,k1}, t1 <- {k2}
// per axis (circular wrap mod 16 matches ((..)mod 32)>>1 exactly).
//
// Round 2: split output channels across 2 blocks (we = 32KB LDS -> 5 blk/CU,
// ~20 waves/CU vs 8 before) + j-unroll x2 with hoisted loads for ILP.

#define B_  4
#define CI  64
#define CO  32
#define IH  16          // output channels per block
#define Q   16          // input spatial size per axis
#define XB_STRIDE (CI*Q*Q*Q)    // 262144
#define OUT_I_STRIDE (32*32*32) // 32768
#define OUT_B_STRIDE (CO*OUT_I_STRIDE)

__global__ __launch_bounds__(256)
void convt3d_parity_kernel(const float* __restrict__ x,
                           const float* __restrict__ weight,
                           float* __restrict__ out) {
    // we[il][j][t], t = td*4+th*2+tw  (32 KB)
    __shared__ float we[IH][CI][8];

    const int blk  = blockIdx.x;
    const int half = blk & 1;           // which 16 output channels
    const int tile = (blk >> 1) & 15;   // qd plane
    const int p    = (blk >> 5) & 7;    // parity
    const int b    = blk >> 8;          // batch
    const int pd = p >> 2, ph = (p >> 1) & 1, pw = p & 1;

    // ---- build effective weights for this parity / channel-half ----
    for (int pair = threadIdx.x; pair < IH * CI; pair += 256) {
        const int il = pair >> 6, j = pair & 63;
        const float* wp = weight + ((half * IH + il) * CI + j) * 27;
        float wv[27];
        #pragma unroll
        for (int k = 0; k < 27; ++k) wv[k] = wp[k];

        float t1[2][9];
        #pragma unroll
        for (int m = 0; m < 9; ++m) {
            t1[0][m] = pd ? (wv[m] + wv[9 + m]) : wv[m];
            t1[1][m] = pd ? wv[18 + m] : (wv[9 + m] + wv[18 + m]);
        }
        float t2[2][2][3];
        #pragma unroll
        for (int td = 0; td < 2; ++td) {
            #pragma unroll
            for (int m = 0; m < 3; ++m) {
                t2[td][0][m] = ph ? (t1[td][m] + t1[td][3 + m]) : t1[td][m];
                t2[td][1][m] = ph ? t1[td][6 + m] : (t1[td][3 + m] + t1[td][6 + m]);
            }
        }
        #pragma unroll
        for (int td = 0; td < 2; ++td) {
            #pragma unroll
            for (int th = 0; th < 2; ++th) {
                float a0 = pw ? (t2[td][th][0] + t2[td][th][1]) : t2[td][th][0];
                float a1 = pw ? t2[td][th][2] : (t2[td][th][1] + t2[td][th][2]);
                we[il][j][td * 4 + th * 2 + 0] = a0;
                we[il][j][td * 4 + th * 2 + 1] = a1;
            }
        }
    }
    __syncthreads();

    // ---- per-thread: one q-position, 16 output channels ----
    const int qd = tile;
    const int qh = threadIdx.x >> 4, qw = threadIdx.x & 15;

    int xoff[8];
    #pragma unroll
    for (int t = 0; t < 8; ++t) {
        const int td = t >> 2, th = (t >> 1) & 1, tw = t & 1;
        xoff[t] = ((qd - td) & 15) * 256 + ((qh - th) & 15) * 16 + ((qw - tw) & 15);
    }

    const float* xb = x + b * XB_STRIDE;
    float acc[IH];
    #pragma unroll
    for (int i = 0; i < IH; ++i) acc[i] = 0.f;

    for (int j = 0; j < CI; j += 2) {
        float xv[2][8];
        #pragma unroll
        for (int t = 0; t < 8; ++t) xv[0][t] = xb[j * (Q*Q*Q) + xoff[t]];
        #pragma unroll
        for (int t = 0; t < 8; ++t) xv[1][t] = xb[(j + 1) * (Q*Q*Q) + xoff[t]];

        #pragma unroll
        for (int u = 0; u < 2; ++u) {
            #pragma unroll
            for (int i = 0; i < IH; ++i) {
                const float4* w4 = reinterpret_cast<const float4*>(&we[i][j + u][0]);
                const float4 wa = w4[0];
                const float4 wb = w4[1];
                acc[i] += wa.x * xv[u][0] + wa.y * xv[u][1]
                        + wa.z * xv[u][2] + wa.w * xv[u][3]
                        + wb.x * xv[u][4] + wb.y * xv[u][5]
                        + wb.z * xv[u][6] + wb.w * xv[u][7];
            }
        }
    }

    const int d = 2 * qd + pd, h = 2 * qh + ph, w_ = 2 * qw + pw;
    float* ob = out + b * OUT_B_STRIDE + d * 1024 + h * 32 + w_
              + half * IH * OUT_I_STRIDE;
    #pragma unroll
    for (int i = 0; i < IH; ++i) ob[i * OUT_I_STRIDE] = acc[i];
}

extern "C" void kernel_launch(void* const* d_in, const int* in_sizes, int n_in,
                              void* d_out, int out_size, void* d_ws, size_t ws_size,
                              hipStream_t stream) {
    const float* x      = (const float*)d_in[0];
    const float* weight = (const float*)d_in[1];
    float* out          = (float*)d_out;

    convt3d_parity_kernel<<<1024, 256, 0, stream>>>(x, weight, out);
}

// Round 3
// 36.850 us; speedup vs baseline: 3.1661x; 3.0449x over previous
//
#include <hip/hip_runtime.h>

// ConvTranspose3d-via-FFT == circular 3^3 conv on 2x-upsampled grid.
// Parity decomposition (verified rounds 0-2): out[b,i,2q+p] = sum_{j,t} We_p[i][j][t] * x[b,j,(q-t) mod 16]
// with per-axis combined weights:
//   p=0: t0 <- k0,    t1 <- k1+k2
//   p=1: t0 <- k0+k1, t1 <- k2
//
// Round 3: cast to bf16 MFMA GEMM. Per (pd,ph) and tap t:
//   out[i, q] += We[(pd,ph,pw)][t][i][:] . xT[b][q - t][:]   (K = 64 input channels)
// xT = x transposed to [b][q][j] so K is contiguous (dwordx4 B-fragments).

typedef float f32x16 __attribute__((ext_vector_type(16)));
typedef short s16x8 __attribute__((ext_vector_type(8)));

#define CI  64
#define CO  32
#define QV  4096          // 16^3
#define OUT_I_STRIDE 32768
#define XT_ELEMS (4 * QV * CI)       // 1048576
#define WE_ELEMS (8 * 8 * CO * CI)   // 131072

__device__ __forceinline__ unsigned short f32_to_bf16_rne(float f) {
    union { float f; unsigned u; } v; v.f = f;
    unsigned u = v.u;
    unsigned r = u + 0x7FFFu + ((u >> 16) & 1u);
    return (unsigned short)(r >> 16);
}

// ---- prep A: xT[b][qd][qh][qw][j] (bf16) from x[b][j][qd][qh][qw] (f32) ----
__global__ __launch_bounds__(256)
void xT_kernel(const float* __restrict__ x, unsigned short* __restrict__ xT) {
    const int t = blockIdx.x * 256 + threadIdx.x;   // 16384 threads: (b, q)
    const int b = t >> 12, q = t & 4095;
    const float* xb = x + b * (CI * QV) + q;
    unsigned short* o = xT + (size_t)t * CI;
    #pragma unroll
    for (int jj = 0; jj < 8; ++jj) {
        s16x8 pk;
        #pragma unroll
        for (int e = 0; e < 8; ++e)
            pk[e] = (short)f32_to_bf16_rne(xb[(jj * 8 + e) * QV]);
        *reinterpret_cast<s16x8*>(o + jj * 8) = pk;
    }
}

// ---- prep B: We[p][t][i][j] (bf16), p = pd*4+ph*2+pw, t = td*4+th*2+tw ----
__global__ __launch_bounds__(256)
void we_kernel(const float* __restrict__ weight, unsigned short* __restrict__ We) {
    const int tid = blockIdx.x * 256 + threadIdx.x;  // 16384: p*2048 + i*64 + j
    const int p = tid >> 11, i = (tid >> 6) & 31, j = tid & 63;
    const int pd = p >> 2, ph = (p >> 1) & 1, pw = p & 1;

    const float* wp = weight + (i * CI + j) * 27;
    float wv[27];
    #pragma unroll
    for (int k = 0; k < 27; ++k) wv[k] = wp[k];

    float t1[2][9];
    #pragma unroll
    for (int m = 0; m < 9; ++m) {
        t1[0][m] = pd ? (wv[m] + wv[9 + m]) : wv[m];
        t1[1][m] = pd ? wv[18 + m] : (wv[9 + m] + wv[18 + m]);
    }
    float t2[2][2][3];
    #pragma unroll
    for (int td = 0; td < 2; ++td)
        #pragma unroll
        for (int m = 0; m < 3; ++m) {
            t2[td][0][m] = ph ? (t1[td][m] + t1[td][3 + m]) : t1[td][m];
            t2[td][1][m] = ph ? t1[td][6 + m] : (t1[td][3 + m] + t1[td][6 + m]);
        }
    #pragma unroll
    for (int td = 0; td < 2; ++td)
        #pragma unroll
        for (int th = 0; th < 2; ++th) {
            float a0 = pw ? (t2[td][th][0] + t2[td][th][1]) : t2[td][th][0];
            float a1 = pw ? t2[td][th][2] : (t2[td][th][1] + t2[td][th][2]);
            const int tA = td * 4 + th * 2 + 0, tB = tA + 1;
            We[((p * 8 + tA) * CO + i) * CI + j] = f32_to_bf16_rne(a0);
            We[((p * 8 + tB) * CO + i) * CI + j] = f32_to_bf16_rne(a1);
        }
}

// ---- main: MFMA GEMM, one wave = one (b, pd, ph, 32-col q-tile), both pw ----
__global__ __launch_bounds__(256)
void convt3d_mfma_kernel(const unsigned short* __restrict__ xT,
                         const unsigned short* __restrict__ We,
                         float* __restrict__ out) {
    const int blk = blockIdx.x;          // 512 blocks
    const int pp  = blk >> 7;            // (pd,ph)
    const int T   = blk & 127;           // q-tile
    const int pd = pp >> 1, ph = pp & 1;

    const int b    = threadIdx.x >> 6;   // wave = batch
    const int l    = threadIdx.x & 63;
    const int n    = l & 31;             // output column (q within tile)
    const int half = l >> 5;             // k-group

    const int qd = T >> 3;
    const int qh = (T & 7) * 2 + (n >> 4);
    const int qw = n & 15;

    const int p0 = pd * 4 + ph * 2;      // pw=0 parity index

    f32x16 acc0 = {};
    f32x16 acc1 = {};

    const unsigned short* xTb = xT + (size_t)b * (QV * CI);

    #pragma unroll
    for (int t = 0; t < 8; ++t) {
        const int td = t >> 2, th = (t >> 1) & 1, tw = t & 1;
        const int dd = (qd - td) & 15, hh = (qh - th) & 15, ww = (qw - tw) & 15;
        const unsigned short* brow  = xTb + ((dd * 16 + hh) * 16 + ww) * CI + half * 8;
        const unsigned short* arow0 = We + ((p0 * 8 + t) * CO + n) * CI + half * 8;
        const unsigned short* arow1 = arow0 + 8 * CO * CI;   // pw=1
        #pragma unroll
        for (int ks = 0; ks < 4; ++ks) {
            const s16x8 bfrag = *reinterpret_cast<const s16x8*>(brow  + ks * 16);
            const s16x8 a0    = *reinterpret_cast<const s16x8*>(arow0 + ks * 16);
            const s16x8 a1    = *reinterpret_cast<const s16x8*>(arow1 + ks * 16);
            acc0 = __builtin_amdgcn_mfma_f32_32x32x16_bf16(a0, bfrag, acc0, 0, 0, 0);
            acc1 = __builtin_amdgcn_mfma_f32_32x32x16_bf16(a1, bfrag, acc1, 0, 0, 0);
        }
    }

    // D layout (m74/m101): col n = l&31, row m = (r&3) + 8*(r>>2) + 4*half
    const int d = 2 * qd + pd, h = 2 * qh + ph, w = 2 * qw;
    #pragma unroll
    for (int r = 0; r < 16; ++r) {
        const int m = (r & 3) + 8 * (r >> 2) + 4 * half;
        float2 v; v.x = acc0[r]; v.y = acc1[r];   // w and w+1 (pw=0,1)
        *reinterpret_cast<float2*>(out + (((size_t)b * CO + m) * 32 + d) * 1024 + h * 32 + w) = v;
    }
}

extern "C" void kernel_launch(void* const* d_in, const int* in_sizes, int n_in,
                              void* d_out, int out_size, void* d_ws, size_t ws_size,
                              hipStream_t stream) {
    const float* x      = (const float*)d_in[0];
    const float* weight = (const float*)d_in[1];
    float* out          = (float*)d_out;

    unsigned short* xT = (unsigned short*)d_ws;
    unsigned short* We = xT + XT_ELEMS;

    xT_kernel<<<64, 256, 0, stream>>>(x, xT);
    we_kernel<<<64, 256, 0, stream>>>(weight, We);
    convt3d_mfma_kernel<<<512, 256, 0, stream>>>(xT, We, out);
}

// Round 4
// 22.110 us; speedup vs baseline: 5.2767x; 1.6666x over previous
//
#include <hip/hip_runtime.h>

// ConvTranspose3d-via-FFT == circular 3^3 conv on 2x-upsampled grid.
// Parity decomposition (verified): out[b,i,2q+p] = sum_{j,t} We_p[i][j][t] * x[b,j,(q-t) mod 16]
//   p=0: t0 <- k0,    t1 <- k1+k2
//   p=1: t0 <- k0+k1, t1 <- k2     (per axis, circular mod 16)
//
// Round 4: fused prep (xT transpose + effective-weight build, full-GPU grid);
// main kernel stages We for its (pd,ph) into 64KB LDS in a lane-consecutive
// [plane16][chunk8][n32][e8] layout (conflict-free ds_read_b128), 8 waves/block.

typedef float f32x16 __attribute__((ext_vector_type(16)));
typedef short s16x8 __attribute__((ext_vector_type(8)));

#define CI  64
#define CO  32
#define QV  4096                     // 16^3
#define XT_ELEMS (4 * QV * CI)       // 1048576 bf16
// WeG layout: [pp=4][plane=16][chunk=8][n=32][e=8] bf16 ; plane = pw*8 + t
#define WE_ELEMS (4 * 16 * 8 * 32 * 8)

__device__ __forceinline__ unsigned short f32_to_bf16_rne(float f) {
    union { float f; unsigned u; } v; v.f = f;
    unsigned u = v.u;
    unsigned r = u + 0x7FFFu + ((u >> 16) & 1u);
    return (unsigned short)(r >> 16);
}

// ---- fused prep: blocks [0,512) transpose x -> xT[b][q][j] bf16;
//      blocks [512,576) build WeG ----
__global__ __launch_bounds__(256)
void prep_kernel(const float* __restrict__ x, const float* __restrict__ weight,
                 unsigned short* __restrict__ xT, unsigned short* __restrict__ WeG) {
    const int blk = blockIdx.x;
    if (blk < 512) {
        const int tid = blk * 256 + threadIdx.x;        // 131072: (b, jj, q)
        const int b  = tid >> 15;
        const int rem = tid & 32767;
        const int jj = rem >> 12;                        // 8 chunks of 8 j
        const int q  = rem & 4095;                       // lane-consecutive
        const float* xb = x + b * (CI * QV) + q;
        s16x8 pk;
        #pragma unroll
        for (int e = 0; e < 8; ++e)
            pk[e] = (short)f32_to_bf16_rne(xb[(jj * 8 + e) * QV]);
        *reinterpret_cast<s16x8*>(xT + ((size_t)(b * QV + q)) * CI + jj * 8) = pk;
    } else {
        const int tid = (blk - 512) * 256 + threadIdx.x; // 16384: p*2048+i*64+j
        const int p = tid >> 11, i = (tid >> 6) & 31, j = tid & 63;
        const int pd = p >> 2, ph = (p >> 1) & 1, pw = p & 1;
        const int pp = pd * 2 + ph;

        const float* wp = weight + (i * CI + j) * 27;
        float wv[27];
        #pragma unroll
        for (int k = 0; k < 27; ++k) wv[k] = wp[k];

        float t1[2][9];
        #pragma unroll
        for (int m = 0; m < 9; ++m) {
            t1[0][m] = pd ? (wv[m] + wv[9 + m]) : wv[m];
            t1[1][m] = pd ? wv[18 + m] : (wv[9 + m] + wv[18 + m]);
        }
        float t2[2][2][3];
        #pragma unroll
        for (int td = 0; td < 2; ++td)
            #pragma unroll
            for (int m = 0; m < 3; ++m) {
                t2[td][0][m] = ph ? (t1[td][m] + t1[td][3 + m]) : t1[td][m];
                t2[td][1][m] = ph ? t1[td][6 + m] : (t1[td][3 + m] + t1[td][6 + m]);
            }

        const int c = j >> 3, e = j & 7;   // k-chunk, element
        #pragma unroll
        for (int td = 0; td < 2; ++td)
            #pragma unroll
            for (int th = 0; th < 2; ++th) {
                float a0 = pw ? (t2[td][th][0] + t2[td][th][1]) : t2[td][th][0];
                float a1 = pw ? t2[td][th][2] : (t2[td][th][1] + t2[td][th][2]);
                const int tA = td * 4 + th * 2;          // tw=0
                const int plane0 = pw * 8 + tA;
                // idx = (((pp*16 + plane)*8 + c)*32 + i)*8 + e
                WeG[(((pp * 16 + plane0) * 8 + c) * 32 + i) * 8 + e]     = f32_to_bf16_rne(a0);
                WeG[(((pp * 16 + plane0 + 1) * 8 + c) * 32 + i) * 8 + e] = f32_to_bf16_rne(a1);
            }
    }
}

// ---- main: 256 blocks x 512 threads; block = (pd,ph) x 2 q-tiles, 8 waves =
//      4 batches x 2 sub-tiles sharing one 64KB LDS copy of We(pd,ph) ----
__global__ __launch_bounds__(512)
void convt3d_mfma_kernel(const unsigned short* __restrict__ xT,
                         const unsigned short* __restrict__ WeG,
                         float* __restrict__ out) {
    __shared__ unsigned short we_lds[16 * 8 * 32 * 8];   // 64 KB

    const int blk = blockIdx.x;          // 256
    const int pp  = blk >> 6;            // (pd,ph)
    const int Tg  = blk & 63;
    const int pd = pp >> 1, ph = pp & 1;

    // stage We(pd,ph): 64KB, 8 passes of 512 threads x 16B (lane-consecutive)
    {
        const char* src = (const char*)(WeG + pp * (16 * 8 * 32 * 8));
        char* dst = (char*)we_lds;
        #pragma unroll
        for (int pass = 0; pass < 8; ++pass) {
            const int off = pass * 8192 + threadIdx.x * 16;
            *reinterpret_cast<s16x8*>(dst + off) =
                *reinterpret_cast<const s16x8*>(src + off);
        }
    }
    __syncthreads();

    const int w    = threadIdx.x >> 6;   // wave 0..7
    const int l    = threadIdx.x & 63;
    const int b    = w >> 1;             // batch
    const int T    = Tg * 2 + (w & 1);   // q-tile 0..127
    const int n    = l & 31;             // output column
    const int half = l >> 5;             // k-group

    const int qd = T >> 3;
    const int qh = (T & 7) * 2 + (n >> 4);
    const int qw = n & 15;

    f32x16 acc0 = {};
    f32x16 acc1 = {};
    const unsigned short* xTb = xT + (size_t)b * (QV * CI);

    #pragma unroll
    for (int t = 0; t < 8; ++t) {
        const int td = t >> 2, th = (t >> 1) & 1, tw = t & 1;
        const int dd = (qd - td) & 15, hh = (qh - th) & 15, ww = (qw - tw) & 15;
        const unsigned short* brow = xTb + ((dd * 16 + hh) * 16 + ww) * CI + half * 8;
        #pragma unroll
        for (int ks = 0; ks < 4; ++ks) {
            const int c = 2 * ks + half;             // j-chunk = (half*8+ks*16)/8
            const s16x8 bfrag = *reinterpret_cast<const s16x8*>(brow + ks * 16);
            const s16x8 a0 = *reinterpret_cast<const s16x8*>(
                we_lds + (((t) * 8 + c) * 32 + n) * 8);
            const s16x8 a1 = *reinterpret_cast<const s16x8*>(
                we_lds + (((8 + t) * 8 + c) * 32 + n) * 8);
            acc0 = __builtin_amdgcn_mfma_f32_32x32x16_bf16(a0, bfrag, acc0, 0, 0, 0);
            acc1 = __builtin_amdgcn_mfma_f32_32x32x16_bf16(a1, bfrag, acc1, 0, 0, 0);
        }
    }

    // D layout: col n = l&31, row m = (r&3) + 8*(r>>2) + 4*half
    const int d = 2 * qd + pd, h = 2 * qh + ph, wq = 2 * qw;
    #pragma unroll
    for (int r = 0; r < 16; ++r) {
        const int m = (r & 3) + 8 * (r >> 2) + 4 * half;
        float2 v; v.x = acc0[r]; v.y = acc1[r];      // pw = 0, 1
        *reinterpret_cast<float2*>(out + (((size_t)b * CO + m) * 32 + d) * 1024 + h * 32 + wq) = v;
    }
}

extern "C" void kernel_launch(void* const* d_in, const int* in_sizes, int n_in,
                              void* d_out, int out_size, void* d_ws, size_t ws_size,
                              hipStream_t stream) {
    const float* x      = (const float*)d_in[0];
    const float* weight = (const float*)d_in[1];
    float* out          = (float*)d_out;

    unsigned short* xT = (unsigned short*)d_ws;
    unsigned short* We = xT + XT_ELEMS;

    prep_kernel<<<576, 256, 0, stream>>>(x, weight, xT, We);
    convt3d_mfma_kernel<<<256, 512, 0, stream>>>(xT, We, out);
}